// Round 19
// baseline (103.758 us; speedup 1.0000x reference)
//
#include <hip/hip_runtime.h>
#include <hip/hip_fp16.h>
#include <cmath>

#define F_IN 8
#define PER 12
#define FEAT 96   // F_IN*PER
#define HID 64
#define CAP 64    // bucket capacity per node (in-degree ~ Poisson(24); P(>=64) ~ 1e-12/node)
#define NB 8      // nodes per block in k_fused
#define EPB 4096  // edges per pass1 block
#define LOG2E 1.44269504088896340736f

static inline size_t al256(size_t x) { return (x + 255) & ~(size_t)255; }

__device__ __forceinline__ float frcp(float x) { return __builtin_amdgcn_rcpf(x); }
__device__ __forceinline__ float fexp2(float x) { return __builtin_amdgcn_exp2f(x); }

// v_fma_mix_f32: acc(f32) += w(f32) * half(lo/hi of 32b reg). Exact f16->f32 + fp32 FMA.
#define MIX_LO(acc, w, bits) \
    asm("v_fma_mix_f32 %0, %1, %2, %0 op_sel_hi:[0,1,0]" : "+v"(acc) : "v"(w), "v"(bits))
#define MIX_HI(acc, w, bits) \
    asm("v_fma_mix_f32 %0, %1, %2, %0 op_sel:[0,1,0] op_sel_hi:[0,1,0]" : "+v"(acc) : "v"(w), "v"(bits))

// ---- shared device helper: fold weights into M (256-thread block) ----
// M layout: [0..511]=Mz, [512..1023]=Mh, [1024..1087]=cz, [1088..1151]=ch, [1152..1163]=probs
// Mz/cz pre-scaled by log2e, Mh/ch by 2*log2e so the GRU uses raw v_exp_f32 (2^x).
__device__ __forceinline__ void fold_weights(int t,
        const float* __restrict__ Wcz, const float* __restrict__ bcz,
        const float* __restrict__ Wch, const float* __restrict__ bch,
        const float* __restrict__ Wlz, const float* __restrict__ blz,
        const float* __restrict__ Wlh, const float* __restrict__ blh,
        const float* __restrict__ att, float* __restrict__ M) {
    int j = t & 63;
    int w = t >> 6;                       // wave w handles f = 2w, 2w+1
#pragma unroll
    for (int q = 0; q < 2; ++q) {
        int f = 2 * w + q;
        float az = 0.f, ah = 0.f;
        for (int k = 0; k < HID; ++k) {
            az = fmaf(Wcz[f * HID + k], Wlz[k * HID + j], az);
            ah = fmaf(Wch[f * HID + k], Wlh[k * HID + j], ah);
        }
        M[f * HID + j] = az * LOG2E;
        M[512 + f * HID + j] = ah * (2.0f * LOG2E);
    }
    if (w == 0) {
        float cz = blz[j], ch = blh[j];
        for (int k = 0; k < HID; ++k) {
            cz = fmaf(bcz[k], Wlz[k * HID + j], cz);
            ch = fmaf(bch[k], Wlh[k * HID + j], ch);
        }
        M[1024 + j] = cz * LOG2E;
        M[1088 + j] = ch * (2.0f * LOG2E);
        if (j < PER) {
            float s = 0.f;
            for (int tt = 0; tt < PER; ++tt) s += expf(att[tt]);
            M[1152 + j] = expf(att[j]) / s;
        }
    }
}

// ================= pass 1: bin edges by dst>>BB, block-aggregated, vectorized =================
// Block 0 additionally folds the weights (hidden under the other blocks' binning).

template <int BB, int BCAP>
__global__ __launch_bounds__(256) void k_pass1(const int* __restrict__ src, const int* __restrict__ dst,
                                               const float* __restrict__ attr,
                                               int* __restrict__ cursor, int2* __restrict__ binned, int e,
                                               const float* __restrict__ Wcz, const float* __restrict__ bcz,
                                               const float* __restrict__ Wch, const float* __restrict__ bch,
                                               const float* __restrict__ Wlz, const float* __restrict__ blz,
                                               const float* __restrict__ Wlh, const float* __restrict__ blh,
                                               const float* __restrict__ att, float* __restrict__ M) {
    constexpr int HSZ = (BB <= 7) ? 512 : 256;
    constexpr int NPv = 1 << BB;
    __shared__ int hist[HSZ];
    __shared__ int base[HSZ];
    int t = threadIdx.x;
    int bs = blockIdx.x * EPB;
    for (int i = t; i < HSZ; i += 256) hist[i] = 0;
    __syncthreads();
    int2 ent[16];
    int  br[16];
    if (bs + EPB <= e && (e & 3) == 0) {
        const int4*   s4 = (const int4*)(src + bs);
        const int4*   d4 = (const int4*)(dst + bs);
        const float4* a4 = (const float4*)(attr + bs);
#pragma unroll
        for (int k = 0; k < 4; ++k) {
            int idx = k * 256 + t;
            int4   ss = s4[idx];
            int4   dd = d4[idx];
            float4 aa = a4[idx];
            int   sv[4] = {ss.x, ss.y, ss.z, ss.w};
            int   dv[4] = {dd.x, dd.y, dd.z, dd.w};
            float av[4] = {aa.x, aa.y, aa.z, aa.w};
#pragma unroll
            for (int u = 0; u < 4; ++u) {
                int d = dv[u];
                int b = d >> BB;
                int rank = atomicAdd(&hist[b], 1);          // LDS atomic
                ent[k * 4 + u].x = sv[u] | ((d & (NPv - 1)) << 20);
                ent[k * 4 + u].y = __float_as_int(av[u]);
                br[k * 4 + u] = (b << 13) | rank;           // rank < 4096 fits 13 bits
            }
        }
    } else {
#pragma unroll
        for (int r = 0; r < 16; ++r) {
            int i = bs + r * 256 + t;
            if (i < e) {
                int d = dst[i];
                int b = d >> BB;
                int rank = atomicAdd(&hist[b], 1);
                ent[r].x = src[i] | ((d & (NPv - 1)) << 20);
                ent[r].y = __float_as_int(attr[i]);
                br[r] = (b << 13) | rank;
            } else br[r] = -1;
        }
    }
    __syncthreads();
    for (int i = t; i < HSZ; i += 256) {
        int h = hist[i];
        if (h > 0) base[i] = atomicAdd(&cursor[i], h);      // one global atomic per bin per block
    }
    __syncthreads();
#pragma unroll
    for (int r = 0; r < 16; ++r) {
        if (br[r] >= 0) {
            int b = br[r] >> 13, rank = br[r] & 8191;
            int pos = base[b] + rank;
            if (pos < BCAP)                                  // overflow impossible; never corrupt
                binned[(size_t)b * BCAP + pos] = ent[r];
        }
    }
    if (blockIdx.x == 0)
        fold_weights(t, Wcz, bcz, Wch, bch, Wlz, blz, Wlh, blh, att, M);
}

// ================= pass 2: per-bin sort + dinv + X->fp16 (fused, int4-paired reads) =============

template <int BB, int BCAP>
__global__ __launch_bounds__(256) void k_pass2x(const int* __restrict__ cursor, const int2* __restrict__ binned,
                                                const float4* __restrict__ X4,
                                                int2* __restrict__ bucket, int* __restrict__ cnt,
                                                float* __restrict__ dinv_g, uint2* __restrict__ Xh2, int n) {
    constexpr int NP = 1 << BB;
    __shared__ int   hist[NP];
    __shared__ float wsum[NP];
    __shared__ float sdv[NP];
    int b = blockIdx.x;
    int t = threadIdx.x;
    if (t < NP) { hist[t] = 0; wsum[t] = 0.f; }
    __syncthreads();
    int m = min(cursor[b], BCAP);
    const int4* bin4 = (const int4*)(binned + (size_t)b * BCAP);   // BCAP even -> aligned
    int half = (m + 1) >> 1;
    for (int i = t; i < half; i += 256) {
        int4 q = bin4[i];                                  // 2 entries per 16B load
        {
            int dl = (q.x >> 20) & (NP - 1);
            atomicAdd(&wsum[dl], __int_as_float(q.y));
            int rank = atomicAdd(&hist[dl], 1);
            if (rank < CAP) {
                int d = (b << BB) | dl;
                bucket[(size_t)d * CAP + rank] = make_int2(q.x & 0xFFFFF, q.y);
            }
        }
        if (2 * i + 1 < m) {
            int dl = (q.z >> 20) & (NP - 1);
            atomicAdd(&wsum[dl], __int_as_float(q.w));
            int rank = atomicAdd(&hist[dl], 1);
            if (rank < CAP) {
                int d = (b << BB) | dl;
                bucket[(size_t)d * CAP + rank] = make_int2(q.z & 0xFFFFF, q.w);
            }
        }
    }
    __syncthreads();
    int node0 = b << BB;
    if (t < NP) {
        int node = node0 + t;
        float dv = 0.f;
        if (node < n) {
            cnt[node] = hist[t];
            dv = rsqrtf(1.0f + wsum[t]);                // 1.0 = self-loop weight
            dinv_g[node] = dv;
        }
        sdv[t] = dv;
    }
    __syncthreads();
    // convert this bin's X rows: X'[node,:] = dinv[node]*X[node,:] -> fp16
    int nn = n - node0; if (nn > NP) nn = NP; if (nn < 0) nn = 0;
    int lim = nn * 24;
    size_t base4 = (size_t)node0 * 24;
    for (int i = t; i < lim; i += 256) {
        int nl = i / 24;
        float s = sdv[nl];
        float4 v = X4[base4 + i];
        __half2 a = __floats2half2_rn(s * v.x, s * v.y);
        __half2 c = __floats2half2_rn(s * v.z, s * v.w);
        uint2 o;
        o.x = __builtin_bit_cast(unsigned int, a);
        o.y = __builtin_bit_cast(unsigned int, c);
        Xh2[base4 + i] = o;
    }
}

// ---------- fallback path kernels (only if workspace too small) ----------

__global__ void k_weights(const float* __restrict__ Wcz, const float* __restrict__ bcz,
                          const float* __restrict__ Wch, const float* __restrict__ bch,
                          const float* __restrict__ Wlz, const float* __restrict__ blz,
                          const float* __restrict__ Wlh, const float* __restrict__ blh,
                          const float* __restrict__ att, float* __restrict__ M) {
    fold_weights((int)threadIdx.x, Wcz, bcz, Wch, bch, Wlz, blz, Wlh, blh, att, M);
}

__global__ void k_zero(int* __restrict__ cnt, int n) {
    int i = blockIdx.x * 256 + threadIdx.x;
    if (i < n) cnt[i] = 0;
}

__global__ void k_bucket(const int* __restrict__ src, const int* __restrict__ dst,
                         const float* __restrict__ attr,
                         int* __restrict__ cnt, int2* __restrict__ bucket, int e) {
    int i = blockIdx.x * 256 + threadIdx.x;
    if (i >= e) return;
    int d = dst[i];
    int pos = atomicAdd(&cnt[d], 1);
    if (pos < CAP) {
        int2 p;
        p.x = src[i];
        p.y = __float_as_int(attr[i]);
        bucket[(size_t)d * CAP + pos] = p;
    }
}

__global__ void k_dinv(const int* __restrict__ cnt, const int2* __restrict__ bucket,
                       float* __restrict__ dinv, int n) {
    int gid = blockIdx.x * 256 + threadIdx.x;
    int node = gid >> 6;
    int lane = gid & 63;
    if (node >= n) return;
    int c = min(cnt[node], CAP);
    float s = (lane < c) ? __int_as_float(bucket[(size_t)node * CAP + lane].y) : 0.f;
#pragma unroll
    for (int d = 32; d; d >>= 1) s += __shfl_xor(s, d);
    if (lane == 0) dinv[node] = rsqrtf(1.0f + s);
}

__global__ void k_xhalf(const float4* __restrict__ X4, const float* __restrict__ dinv,
                        uint2* __restrict__ Xh2, int total4) {
    int i = blockIdx.x * 256 + threadIdx.x;
    if (i >= total4) return;
    int node = i / 24;
    float s = dinv[node];
    float4 v = X4[i];
    __half2 a = __floats2half2_rn(s * v.x, s * v.y);
    __half2 b = __floats2half2_rn(s * v.z, s * v.w);
    uint2 o;
    o.x = __builtin_bit_cast(unsigned int, a);
    o.y = __builtin_bit_cast(unsigned int, b);
    Xh2[i] = o;
}

// ================= fused: stage -> 3-deep pipelined fma_mix gather -> fused-rcp GRU -> readout ==
// r = dv * ( X'_self + sum_e attr * X'_src ),  X' = dinv*x  (fp16 rows)
// 3 quads (up to 12 loads) in flight per lane-group to cover L2/L3 gather latency.

#define EDGEA(ew, rr)                                  \
    {                                                  \
        float w_ = __int_as_float((ew).y);             \
        MIX_LO(accA0, w_, (rr).x);                     \
        MIX_HI(accA1, w_, (rr).x);                     \
        MIX_LO(accA2, w_, (rr).y);                     \
        MIX_HI(accA3, w_, (rr).y);                     \
    }
#define EDGEB(ew, rr)                                  \
    {                                                  \
        float w_ = __int_as_float((ew).y);             \
        MIX_LO(accB0, w_, (rr).x);                     \
        MIX_HI(accB1, w_, (rr).x);                     \
        MIX_LO(accB2, w_, (rr).y);                     \
        MIX_HI(accB3, w_, (rr).y);                     \
    }
#define LOADQ(E0, E1, E2, E3, R0, R1, R2, R3, eidx)    \
    E0 = sw[(eidx)];     E1 = sw[(eidx) + 1];          \
    E2 = sw[(eidx) + 2]; E3 = sw[(eidx) + 3];          \
    R0 = Xh2[(unsigned)(E0.x + l)];                    \
    R1 = Xh2[(unsigned)(E1.x + l)];                    \
    R2 = Xh2[(unsigned)(E2.x + l)];                    \
    R3 = Xh2[(unsigned)(E3.x + l)];
#define PROCQ(E0, E1, E2, E3, R0, R1, R2, R3)          \
    EDGEA(E0, R0); EDGEB(E1, R1);                      \
    EDGEA(E2, R2); EDGEB(E3, R3);

__global__ __launch_bounds__(256) void k_fused(const int* __restrict__ cnt,
                                               const int2* __restrict__ bucket,
                                               const float* __restrict__ dinv,
                                               const uint2* __restrict__ Xh2,
                                               const float* __restrict__ M,
                                               const float* __restrict__ Wout,
                                               const float* __restrict__ bout,
                                               float* __restrict__ out, int n) {
    __shared__ int2  s_ew[NB][CAP];     // (src*24, attr) packed: 1 ds_read_b64 per edge
    __shared__ int   s_cnt[NB];
    __shared__ float s_dv[NB];
    __shared__ float s_xp[NB][104];     // 96 + pad
    __shared__ float s_acc[NB][HID + 1];
    int t = threadIdx.x;
    int node0 = blockIdx.x * NB;

    if (t < NB) {
        int node = node0 + t;
        s_cnt[t] = (node < n) ? min(cnt[node], CAP) : 0;
        s_dv[t]  = (node < n) ? dinv[node] : 0.f;
    }
    __syncthreads();

    // ---- Phase A: stage buckets (coalesced) ----
#pragma unroll
    for (int idx = t; idx < NB * CAP; idx += 256) {
        int ln = idx >> 6;          // CAP == 64
        int e  = idx & (CAP - 1);
        if (e < s_cnt[ln]) {
            int2 p = bucket[(size_t)(node0 + ln) * CAP + e];
            s_ew[ln][e] = make_int2(p.x * 24, p.y);     // row offset (uint2 units), attr
        }
    }
    __syncthreads();

    // ---- Phase B: 3-deep pipelined gather ----
    {
        int g32 = t >> 5;
        int l = t & 31;
        int node = node0 + g32;
        if (node < n && l < 24) {
            float dv = s_dv[g32];
            int c = s_cnt[g32];
            const int2* sw = s_ew[g32];
            uint2 sh = Xh2[(unsigned)(node * 24 + l)];  // self row
            float accA0 = 0.f, accA1 = 0.f, accA2 = 0.f, accA3 = 0.f;
            float accB0 = 0.f, accB1 = 0.f, accB2 = 0.f, accB3 = 0.f;
            {   // init accA from self row via fma_mix (w = 1)
                float one = 1.0f;
                MIX_LO(accA0, one, sh.x);
                MIX_HI(accA1, one, sh.x);
                MIX_LO(accA2, one, sh.y);
                MIX_HI(accA3, one, sh.y);
            }
            int e = 0;
            if (c >= 8) {
                int2  a0, a1, a2, a3, b0, b1, b2, b3, c0, c1, c2, c3;
                uint2 ar0, ar1, ar2, ar3, br0, br1, br2, br3, cr0, cr1, cr2, cr3;
                LOADQ(a0, a1, a2, a3, ar0, ar1, ar2, ar3, 0);
                LOADQ(b0, b1, b2, b3, br0, br1, br2, br3, 4);
                for (; e + 20 <= c; e += 12) {
                    LOADQ(c0, c1, c2, c3, cr0, cr1, cr2, cr3, e + 8);
                    PROCQ(a0, a1, a2, a3, ar0, ar1, ar2, ar3);
                    LOADQ(a0, a1, a2, a3, ar0, ar1, ar2, ar3, e + 12);
                    PROCQ(b0, b1, b2, b3, br0, br1, br2, br3);
                    LOADQ(b0, b1, b2, b3, br0, br1, br2, br3, e + 16);
                    PROCQ(c0, c1, c2, c3, cr0, cr1, cr2, cr3);
                }
                // loaded, unprocessed: A@e, B@e+4; c-e in [8, 19]
                if (e + 12 <= c) {
                    LOADQ(c0, c1, c2, c3, cr0, cr1, cr2, cr3, e + 8);
                    PROCQ(a0, a1, a2, a3, ar0, ar1, ar2, ar3);
                    PROCQ(b0, b1, b2, b3, br0, br1, br2, br3);
                    PROCQ(c0, c1, c2, c3, cr0, cr1, cr2, cr3);
                    e += 12;
                } else {
                    PROCQ(a0, a1, a2, a3, ar0, ar1, ar2, ar3);
                    PROCQ(b0, b1, b2, b3, br0, br1, br2, br3);
                    e += 8;
                }
            } else if (c >= 4) {
                int2  a0, a1, a2, a3;
                uint2 ar0, ar1, ar2, ar3;
                LOADQ(a0, a1, a2, a3, ar0, ar1, ar2, ar3, 0);
                PROCQ(a0, a1, a2, a3, ar0, ar1, ar2, ar3);
                e = 4;
            }
            for (; e < c; ++e) {
                int2 e0 = sw[e];
                uint2 r0 = Xh2[(unsigned)(e0.x + l)];
                EDGEA(e0, r0);
            }
            float4 r;
            r.x = dv * (accA0 + accB0);
            r.y = dv * (accA1 + accB1);
            r.z = dv * (accA2 + accB2);
            r.w = dv * (accA3 + accB3);
            *(float4*)&s_xp[g32][l * 4] = r;
        }
    }
    __syncthreads();

    // ---- Phase C: GRU over 12 periods (exp2 weights, single fused rcp) ----
    // (1 - sigmoid(xz))*tanh(xh) = (B-1) / ((1+A)(1+B)),  A=2^xz', B=2^xh'
    {
        int lane = t & 63;
        int wv = t >> 6;
        float mz[F_IN], mh[F_IN];
#pragma unroll
        for (int f = 0; f < F_IN; ++f) {
            mz[f] = M[f * HID + lane];
            mh[f] = M[512 + f * HID + lane];
        }
        float cz = M[1024 + lane], ch = M[1088 + lane];
        float pr[PER];
#pragma unroll
        for (int tt = 0; tt < PER; ++tt) pr[tt] = M[1152 + tt];

#pragma unroll
        for (int q = 0; q < 2; ++q) {
            int ln = wv * 2 + q;
            if (node0 + ln < n) {
                float acc = 0.f;
#pragma unroll
                for (int tt = 0; tt < PER; ++tt) {
                    float xz = cz, xh = ch;
#pragma unroll
                    for (int f = 0; f < F_IN; ++f) {
                        float xv = s_xp[ln][f * PER + tt];   // wave-uniform broadcast
                        xz = fmaf(xv, mz[f], xz);
                        xh = fmaf(xv, mh[f], xh);
                    }
                    float A = fexp2(xz);
                    float B = fexp2(xh);
                    float r = frcp((1.f + A) * (1.f + B));
                    acc = fmaf(pr[tt] * (B - 1.f), r, acc);
                }
                s_acc[ln][lane] = fmaxf(acc, 0.f);
            }
        }
    }
    __syncthreads();

    // ---- Phase D: readout ----
    if (t < NB * PER) {
        int ln = t / PER;
        int pp = t - ln * PER;
        int node = node0 + ln;
        if (node < n) {
            float o = bout[pp];
#pragma unroll
            for (int j = 0; j < HID; ++j) o = fmaf(s_acc[ln][j], Wout[j * PER + pp], o);
            out[(size_t)node * PER + pp] = o;
        }
    }
}

// ================= launch =================

extern "C" void kernel_launch(void* const* d_in, const int* in_sizes, int n_in,
                              void* d_out, int out_size, void* d_ws, size_t ws_size,
                              hipStream_t stream) {
    const float* X     = (const float*)d_in[0];
    const int*   ei    = (const int*)d_in[1];
    const float* attr  = (const float*)d_in[2];
    const float* att   = (const float*)d_in[3];
    const float* Wcz   = (const float*)d_in[4];
    const float* bcz   = (const float*)d_in[5];
    // d_in[6], d_in[7] = Wcr, bcr -- dead (H0 == 0 kills the R path)
    const float* Wch   = (const float*)d_in[8];
    const float* bch   = (const float*)d_in[9];
    const float* Wlz   = (const float*)d_in[10];
    const float* blz   = (const float*)d_in[11];
    // d_in[12], d_in[13] = Wlr, blr -- dead
    const float* Wlh   = (const float*)d_in[14];
    const float* blh   = (const float*)d_in[15];
    const float* Wout  = (const float*)d_in[16];
    const float* bout  = (const float*)d_in[17];
    float* out = (float*)d_out;

    const int N = in_sizes[0] / FEAT;
    const int E = in_sizes[2];
    const int* src = ei;
    const int* dst = ei + E;

    const int total4 = N * (FEAT / 4);
    const int NB7 = (N + 127) >> 7;      // bins at BB=7
    const int NB8 = (N + 255) >> 8;      // bins at BB=8

    // workspace layout
    char* base = (char*)d_ws;
    size_t o = 0;
    int*   cnt    = (int*)  (base + o); o += al256((size_t)N * 4);
    float* dinv   = (float*)(base + o); o += al256((size_t)N * 4);
    float* M      = (float*)(base + o); o += al256(1280 * 4);
    int2*  bucket = (int2*) (base + o); o += al256((size_t)N * CAP * 8);
    uint2* Xh2    = (uint2*)(base + o); o += al256((size_t)N * FEAT * 2);
    int*   cursor = (int*)  (base + o); o += al256(512 * 4);
    int2*  binned = (int2*) (base + o);
    size_t need7 = o + al256((size_t)NB7 * 3968 * 8);
    size_t need8 = o + al256((size_t)NB8 * 7168 * 8);

    if (ws_size >= need7 && NB7 <= 512 && N < (1 << 20)) {
        // BB=7: 391 bins; weights folded into pass1 block 0; cursor via memset
        hipMemsetAsync(cursor, 0, 512 * 4, stream);
        k_pass1<7, 3968><<<(E + EPB - 1) / EPB, 256, 0, stream>>>(src, dst, attr, cursor, binned, E,
                                                                  Wcz, bcz, Wch, bch, Wlz, blz, Wlh, blh, att, M);
        k_pass2x<7, 3968><<<NB7, 256, 0, stream>>>(cursor, binned, (const float4*)X, bucket, cnt, dinv, Xh2, N);
    } else if (ws_size >= need8 && NB8 <= 256 && N < (1 << 20)) {
        hipMemsetAsync(cursor, 0, 512 * 4, stream);
        k_pass1<8, 7168><<<(E + EPB - 1) / EPB, 256, 0, stream>>>(src, dst, attr, cursor, binned, E,
                                                                  Wcz, bcz, Wch, bch, Wlz, blz, Wlh, blh, att, M);
        k_pass2x<8, 7168><<<NB8, 256, 0, stream>>>(cursor, binned, (const float4*)X, bucket, cnt, dinv, Xh2, N);
    } else {
        k_weights<<<1, 256, 0, stream>>>(Wcz, bcz, Wch, bch, Wlz, blz, Wlh, blh, att, M);
        k_zero<<<(N + 255) / 256, 256, 0, stream>>>(cnt, N);
        k_bucket<<<(E + 255) / 256, 256, 0, stream>>>(src, dst, attr, cnt, bucket, E);
        k_dinv<<<((N * 64) + 255) / 256, 256, 0, stream>>>(cnt, bucket, dinv, N);
        k_xhalf<<<(total4 + 255) / 256, 256, 0, stream>>>((const float4*)X, dinv, Xh2, total4);
    }

    int blocks = (N + NB - 1) / NB;
    k_fused<<<blocks, 256, 0, stream>>>(cnt, bucket, dinv, Xh2, M, Wout, bout, out, N);
}

// Round 20
// 102.875 us; speedup vs baseline: 1.0086x; 1.0086x over previous
//
#include <hip/hip_runtime.h>
#include <hip/hip_fp16.h>
#include <cmath>

#define F_IN 8
#define PER 12
#define FEAT 96   // F_IN*PER
#define HID 64
#define CAP 64    // bucket capacity per node (in-degree ~ Poisson(24); P(>=64) ~ 1e-12/node)
#define NB 8      // nodes per block in k_fused
#define EPB 4096  // edges per pass1 block
#define LOG2E 1.44269504088896340736f

static inline size_t al256(size_t x) { return (x + 255) & ~(size_t)255; }

__device__ __forceinline__ float frcp(float x) { return __builtin_amdgcn_rcpf(x); }
__device__ __forceinline__ float fexp2(float x) { return __builtin_amdgcn_exp2f(x); }

// v_fma_mix_f32: acc(f32) += w(f32) * half(lo/hi of 32b reg). Exact f16->f32 + fp32 FMA.
#define MIX_LO(acc, w, bits) \
    asm("v_fma_mix_f32 %0, %1, %2, %0 op_sel_hi:[0,1,0]" : "+v"(acc) : "v"(w), "v"(bits))
#define MIX_HI(acc, w, bits) \
    asm("v_fma_mix_f32 %0, %1, %2, %0 op_sel:[0,1,0] op_sel_hi:[0,1,0]" : "+v"(acc) : "v"(w), "v"(bits))

// ---- shared device helper: fold weights into M (256-thread block) ----
// M layout: [0..511]=Mz, [512..1023]=Mh, [1024..1087]=cz, [1088..1151]=ch, [1152..1163]=probs
// Mz/cz pre-scaled by log2e, Mh/ch by 2*log2e so the GRU uses raw v_exp_f32 (2^x).
__device__ __forceinline__ void fold_weights(int t,
        const float* __restrict__ Wcz, const float* __restrict__ bcz,
        const float* __restrict__ Wch, const float* __restrict__ bch,
        const float* __restrict__ Wlz, const float* __restrict__ blz,
        const float* __restrict__ Wlh, const float* __restrict__ blh,
        const float* __restrict__ att, float* __restrict__ M) {
    int j = t & 63;
    int w = t >> 6;                       // wave w handles f = 2w, 2w+1
#pragma unroll
    for (int q = 0; q < 2; ++q) {
        int f = 2 * w + q;
        float az = 0.f, ah = 0.f;
        for (int k = 0; k < HID; ++k) {
            az = fmaf(Wcz[f * HID + k], Wlz[k * HID + j], az);
            ah = fmaf(Wch[f * HID + k], Wlh[k * HID + j], ah);
        }
        M[f * HID + j] = az * LOG2E;
        M[512 + f * HID + j] = ah * (2.0f * LOG2E);
    }
    if (w == 0) {
        float cz = blz[j], ch = blh[j];
        for (int k = 0; k < HID; ++k) {
            cz = fmaf(bcz[k], Wlz[k * HID + j], cz);
            ch = fmaf(bch[k], Wlh[k * HID + j], ch);
        }
        M[1024 + j] = cz * LOG2E;
        M[1088 + j] = ch * (2.0f * LOG2E);
        if (j < PER) {
            float s = 0.f;
            for (int tt = 0; tt < PER; ++tt) s += expf(att[tt]);
            M[1152 + j] = expf(att[j]) / s;
        }
    }
}

// ================= pass 1: bin edges by dst>>BB, block-aggregated, vectorized =================
// Block 0 additionally folds the weights (hidden under the other blocks' binning).

template <int BB, int BCAP>
__global__ __launch_bounds__(256) void k_pass1(const int* __restrict__ src, const int* __restrict__ dst,
                                               const float* __restrict__ attr,
                                               int* __restrict__ cursor, int2* __restrict__ binned, int e,
                                               const float* __restrict__ Wcz, const float* __restrict__ bcz,
                                               const float* __restrict__ Wch, const float* __restrict__ bch,
                                               const float* __restrict__ Wlz, const float* __restrict__ blz,
                                               const float* __restrict__ Wlh, const float* __restrict__ blh,
                                               const float* __restrict__ att, float* __restrict__ M) {
    constexpr int HSZ = (BB <= 7) ? 512 : 256;
    constexpr int NPv = 1 << BB;
    __shared__ int hist[HSZ];
    __shared__ int base[HSZ];
    int t = threadIdx.x;
    int bs = blockIdx.x * EPB;
    for (int i = t; i < HSZ; i += 256) hist[i] = 0;
    __syncthreads();
    int2 ent[16];
    int  br[16];
    if (bs + EPB <= e && (e & 3) == 0) {
        const int4*   s4 = (const int4*)(src + bs);
        const int4*   d4 = (const int4*)(dst + bs);
        const float4* a4 = (const float4*)(attr + bs);
#pragma unroll
        for (int k = 0; k < 4; ++k) {
            int idx = k * 256 + t;
            int4   ss = s4[idx];
            int4   dd = d4[idx];
            float4 aa = a4[idx];
            int   sv[4] = {ss.x, ss.y, ss.z, ss.w};
            int   dv[4] = {dd.x, dd.y, dd.z, dd.w};
            float av[4] = {aa.x, aa.y, aa.z, aa.w};
#pragma unroll
            for (int u = 0; u < 4; ++u) {
                int d = dv[u];
                int b = d >> BB;
                int rank = atomicAdd(&hist[b], 1);          // LDS atomic
                ent[k * 4 + u].x = sv[u] | ((d & (NPv - 1)) << 20);
                ent[k * 4 + u].y = __float_as_int(av[u]);
                br[k * 4 + u] = (b << 13) | rank;           // rank < 4096 fits 13 bits
            }
        }
    } else {
#pragma unroll
        for (int r = 0; r < 16; ++r) {
            int i = bs + r * 256 + t;
            if (i < e) {
                int d = dst[i];
                int b = d >> BB;
                int rank = atomicAdd(&hist[b], 1);
                ent[r].x = src[i] | ((d & (NPv - 1)) << 20);
                ent[r].y = __float_as_int(attr[i]);
                br[r] = (b << 13) | rank;
            } else br[r] = -1;
        }
    }
    __syncthreads();
    for (int i = t; i < HSZ; i += 256) {
        int h = hist[i];
        if (h > 0) base[i] = atomicAdd(&cursor[i], h);      // one global atomic per bin per block
    }
    __syncthreads();
#pragma unroll
    for (int r = 0; r < 16; ++r) {
        if (br[r] >= 0) {
            int b = br[r] >> 13, rank = br[r] & 8191;
            int pos = base[b] + rank;
            if (pos < BCAP)                                  // overflow impossible; never corrupt
                binned[(size_t)b * BCAP + pos] = ent[r];
        }
    }
    if (blockIdx.x == 0)
        fold_weights(t, Wcz, bcz, Wch, bch, Wlz, blz, Wlh, blh, att, M);
}

// ================= pass 2: per-bin sort + dinv + X->fp16 (fused, int4-paired reads) =============

template <int BB, int BCAP>
__global__ __launch_bounds__(256) void k_pass2x(const int* __restrict__ cursor, const int2* __restrict__ binned,
                                                const float4* __restrict__ X4,
                                                int2* __restrict__ bucket, int* __restrict__ cnt,
                                                float* __restrict__ dinv_g, uint2* __restrict__ Xh2, int n) {
    constexpr int NP = 1 << BB;
    __shared__ int   hist[NP];
    __shared__ float wsum[NP];
    __shared__ float sdv[NP];
    int b = blockIdx.x;
    int t = threadIdx.x;
    if (t < NP) { hist[t] = 0; wsum[t] = 0.f; }
    __syncthreads();
    int m = min(cursor[b], BCAP);
    const int4* bin4 = (const int4*)(binned + (size_t)b * BCAP);   // BCAP even -> aligned
    int half = (m + 1) >> 1;
    for (int i = t; i < half; i += 256) {
        int4 q = bin4[i];                                  // 2 entries per 16B load
        {
            int dl = (q.x >> 20) & (NP - 1);
            atomicAdd(&wsum[dl], __int_as_float(q.y));
            int rank = atomicAdd(&hist[dl], 1);
            if (rank < CAP) {
                int d = (b << BB) | dl;
                bucket[(size_t)d * CAP + rank] = make_int2(q.x & 0xFFFFF, q.y);
            }
        }
        if (2 * i + 1 < m) {
            int dl = (q.z >> 20) & (NP - 1);
            atomicAdd(&wsum[dl], __int_as_float(q.w));
            int rank = atomicAdd(&hist[dl], 1);
            if (rank < CAP) {
                int d = (b << BB) | dl;
                bucket[(size_t)d * CAP + rank] = make_int2(q.z & 0xFFFFF, q.w);
            }
        }
    }
    __syncthreads();
    int node0 = b << BB;
    if (t < NP) {
        int node = node0 + t;
        float dv = 0.f;
        if (node < n) {
            cnt[node] = hist[t];
            dv = rsqrtf(1.0f + wsum[t]);                // 1.0 = self-loop weight
            dinv_g[node] = dv;
        }
        sdv[t] = dv;
    }
    __syncthreads();
    // convert this bin's X rows: X'[node,:] = dinv[node]*X[node,:] -> fp16
    int nn = n - node0; if (nn > NP) nn = NP; if (nn < 0) nn = 0;
    int lim = nn * 24;
    size_t base4 = (size_t)node0 * 24;
    for (int i = t; i < lim; i += 256) {
        int nl = i / 24;
        float s = sdv[nl];
        float4 v = X4[base4 + i];
        __half2 a = __floats2half2_rn(s * v.x, s * v.y);
        __half2 c = __floats2half2_rn(s * v.z, s * v.w);
        uint2 o;
        o.x = __builtin_bit_cast(unsigned int, a);
        o.y = __builtin_bit_cast(unsigned int, c);
        Xh2[base4 + i] = o;
    }
}

// ---------- fallback path kernels (only if workspace too small) ----------

__global__ void k_weights(const float* __restrict__ Wcz, const float* __restrict__ bcz,
                          const float* __restrict__ Wch, const float* __restrict__ bch,
                          const float* __restrict__ Wlz, const float* __restrict__ blz,
                          const float* __restrict__ Wlh, const float* __restrict__ blh,
                          const float* __restrict__ att, float* __restrict__ M) {
    fold_weights((int)threadIdx.x, Wcz, bcz, Wch, bch, Wlz, blz, Wlh, blh, att, M);
}

__global__ void k_zero(int* __restrict__ cnt, int n) {
    int i = blockIdx.x * 256 + threadIdx.x;
    if (i < n) cnt[i] = 0;
}

__global__ void k_bucket(const int* __restrict__ src, const int* __restrict__ dst,
                         const float* __restrict__ attr,
                         int* __restrict__ cnt, int2* __restrict__ bucket, int e) {
    int i = blockIdx.x * 256 + threadIdx.x;
    if (i >= e) return;
    int d = dst[i];
    int pos = atomicAdd(&cnt[d], 1);
    if (pos < CAP) {
        int2 p;
        p.x = src[i];
        p.y = __float_as_int(attr[i]);
        bucket[(size_t)d * CAP + pos] = p;
    }
}

__global__ void k_dinv(const int* __restrict__ cnt, const int2* __restrict__ bucket,
                       float* __restrict__ dinv, int n) {
    int gid = blockIdx.x * 256 + threadIdx.x;
    int node = gid >> 6;
    int lane = gid & 63;
    if (node >= n) return;
    int c = min(cnt[node], CAP);
    float s = (lane < c) ? __int_as_float(bucket[(size_t)node * CAP + lane].y) : 0.f;
#pragma unroll
    for (int d = 32; d; d >>= 1) s += __shfl_xor(s, d);
    if (lane == 0) dinv[node] = rsqrtf(1.0f + s);
}

__global__ void k_xhalf(const float4* __restrict__ X4, const float* __restrict__ dinv,
                        uint2* __restrict__ Xh2, int total4) {
    int i = blockIdx.x * 256 + threadIdx.x;
    if (i >= total4) return;
    int node = i / 24;
    float s = dinv[node];
    float4 v = X4[i];
    __half2 a = __floats2half2_rn(s * v.x, s * v.y);
    __half2 b = __floats2half2_rn(s * v.z, s * v.w);
    uint2 o;
    o.x = __builtin_bit_cast(unsigned int, a);
    o.y = __builtin_bit_cast(unsigned int, b);
    Xh2[i] = o;
}

// ================= fused: stage -> ping-pong fma_mix gather -> fused-rcp GRU -> readout ========
// r = dv * ( X'_self + sum_e attr * X'_src ),  X' = dinv*x  (fp16 rows)
// 32-bit indices throughout the gather -> saddr-form global loads (1 VALU per load).
// 2-deep ping-pong pipeline: R19 proved 3-deep is neutral-to-negative (TLP-saturated).

#define EDGEA(ew, rr)                                  \
    {                                                  \
        float w_ = __int_as_float((ew).y);             \
        MIX_LO(accA0, w_, (rr).x);                     \
        MIX_HI(accA1, w_, (rr).x);                     \
        MIX_LO(accA2, w_, (rr).y);                     \
        MIX_HI(accA3, w_, (rr).y);                     \
    }
#define EDGEB(ew, rr)                                  \
    {                                                  \
        float w_ = __int_as_float((ew).y);             \
        MIX_LO(accB0, w_, (rr).x);                     \
        MIX_HI(accB1, w_, (rr).x);                     \
        MIX_LO(accB2, w_, (rr).y);                     \
        MIX_HI(accB3, w_, (rr).y);                     \
    }
#define LOADQ(E0, E1, E2, E3, R0, R1, R2, R3, eidx)    \
    E0 = sw[(eidx)];     E1 = sw[(eidx) + 1];          \
    E2 = sw[(eidx) + 2]; E3 = sw[(eidx) + 3];          \
    R0 = Xh2[(unsigned)(E0.x + l)];                    \
    R1 = Xh2[(unsigned)(E1.x + l)];                    \
    R2 = Xh2[(unsigned)(E2.x + l)];                    \
    R3 = Xh2[(unsigned)(E3.x + l)];
#define PROCQ(E0, E1, E2, E3, R0, R1, R2, R3)          \
    EDGEA(E0, R0); EDGEB(E1, R1);                      \
    EDGEA(E2, R2); EDGEB(E3, R3);

__global__ __launch_bounds__(256) void k_fused(const int* __restrict__ cnt,
                                               const int2* __restrict__ bucket,
                                               const float* __restrict__ dinv,
                                               const uint2* __restrict__ Xh2,
                                               const float* __restrict__ M,
                                               const float* __restrict__ Wout,
                                               const float* __restrict__ bout,
                                               float* __restrict__ out, int n) {
    __shared__ int2  s_ew[NB][CAP];     // (src*24, attr) packed: 1 ds_read_b64 per edge
    __shared__ int   s_cnt[NB];
    __shared__ float s_dv[NB];
    __shared__ float s_xp[NB][104];     // 96 + pad
    __shared__ float s_acc[NB][HID + 1];
    int t = threadIdx.x;
    int node0 = blockIdx.x * NB;

    if (t < NB) {
        int node = node0 + t;
        s_cnt[t] = (node < n) ? min(cnt[node], CAP) : 0;
        s_dv[t]  = (node < n) ? dinv[node] : 0.f;
    }
    __syncthreads();

    // ---- Phase A: stage buckets (coalesced) ----
#pragma unroll
    for (int idx = t; idx < NB * CAP; idx += 256) {
        int ln = idx >> 6;          // CAP == 64
        int e  = idx & (CAP - 1);
        if (e < s_cnt[ln]) {
            int2 p = bucket[(size_t)(node0 + ln) * CAP + e];
            s_ew[ln][e] = make_int2(p.x * 24, p.y);     // row offset (uint2 units), attr
        }
    }
    __syncthreads();

    // ---- Phase B: ping-pong pipelined gather (no register rotate) ----
    {
        int g32 = t >> 5;
        int l = t & 31;
        int node = node0 + g32;
        if (node < n && l < 24) {
            float dv = s_dv[g32];
            int c = s_cnt[g32];
            const int2* sw = s_ew[g32];
            uint2 sh = Xh2[(unsigned)(node * 24 + l)];  // self row
            float accA0 = 0.f, accA1 = 0.f, accA2 = 0.f, accA3 = 0.f;
            float accB0 = 0.f, accB1 = 0.f, accB2 = 0.f, accB3 = 0.f;
            {   // init accA from self row via fma_mix (w = 1)
                float one = 1.0f;
                MIX_LO(accA0, one, sh.x);
                MIX_HI(accA1, one, sh.x);
                MIX_LO(accA2, one, sh.y);
                MIX_HI(accA3, one, sh.y);
            }
            int e = 0;
            if (c >= 4) {
                int2  a0, a1, a2, a3, b0, b1, b2, b3;
                uint2 ar0, ar1, ar2, ar3, br0, br1, br2, br3;
                LOADQ(a0, a1, a2, a3, ar0, ar1, ar2, ar3, 0);
                for (; e + 12 <= c; e += 8) {
                    LOADQ(b0, b1, b2, b3, br0, br1, br2, br3, e + 4);
                    PROCQ(a0, a1, a2, a3, ar0, ar1, ar2, ar3);
                    LOADQ(a0, a1, a2, a3, ar0, ar1, ar2, ar3, e + 8);
                    PROCQ(b0, b1, b2, b3, br0, br1, br2, br3);
                }
                PROCQ(a0, a1, a2, a3, ar0, ar1, ar2, ar3);
                e += 4;
            }
            for (; e < c; ++e) {
                int2 e0 = sw[e];
                uint2 r0 = Xh2[(unsigned)(e0.x + l)];
                EDGEA(e0, r0);
            }
            float4 r;
            r.x = dv * (accA0 + accB0);
            r.y = dv * (accA1 + accB1);
            r.z = dv * (accA2 + accB2);
            r.w = dv * (accA3 + accB3);
            *(float4*)&s_xp[g32][l * 4] = r;
        }
    }
    __syncthreads();

    // ---- Phase C: GRU over 12 periods (exp2 weights, single fused rcp) ----
    // (1 - sigmoid(xz))*tanh(xh) = (B-1) / ((1+A)(1+B)),  A=2^xz', B=2^xh'
    {
        int lane = t & 63;
        int wv = t >> 6;
        float mz[F_IN], mh[F_IN];
#pragma unroll
        for (int f = 0; f < F_IN; ++f) {
            mz[f] = M[f * HID + lane];
            mh[f] = M[512 + f * HID + lane];
        }
        float cz = M[1024 + lane], ch = M[1088 + lane];
        float pr[PER];
#pragma unroll
        for (int tt = 0; tt < PER; ++tt) pr[tt] = M[1152 + tt];

#pragma unroll
        for (int q = 0; q < 2; ++q) {
            int ln = wv * 2 + q;
            if (node0 + ln < n) {
                float acc = 0.f;
#pragma unroll
                for (int tt = 0; tt < PER; ++tt) {
                    float xz = cz, xh = ch;
#pragma unroll
                    for (int f = 0; f < F_IN; ++f) {
                        float xv = s_xp[ln][f * PER + tt];   // wave-uniform broadcast
                        xz = fmaf(xv, mz[f], xz);
                        xh = fmaf(xv, mh[f], xh);
                    }
                    float A = fexp2(xz);
                    float B = fexp2(xh);
                    float r = frcp((1.f + A) * (1.f + B));
                    acc = fmaf(pr[tt] * (B - 1.f), r, acc);
                }
                s_acc[ln][lane] = fmaxf(acc, 0.f);
            }
        }
    }
    __syncthreads();

    // ---- Phase D: readout ----
    if (t < NB * PER) {
        int ln = t / PER;
        int pp = t - ln * PER;
        int node = node0 + ln;
        if (node < n) {
            float o = bout[pp];
#pragma unroll
            for (int j = 0; j < HID; ++j) o = fmaf(s_acc[ln][j], Wout[j * PER + pp], o);
            out[(size_t)node * PER + pp] = o;
        }
    }
}

// ================= launch =================

extern "C" void kernel_launch(void* const* d_in, const int* in_sizes, int n_in,
                              void* d_out, int out_size, void* d_ws, size_t ws_size,
                              hipStream_t stream) {
    const float* X     = (const float*)d_in[0];
    const int*   ei    = (const int*)d_in[1];
    const float* attr  = (const float*)d_in[2];
    const float* att   = (const float*)d_in[3];
    const float* Wcz   = (const float*)d_in[4];
    const float* bcz   = (const float*)d_in[5];
    // d_in[6], d_in[7] = Wcr, bcr -- dead (H0 == 0 kills the R path)
    const float* Wch   = (const float*)d_in[8];
    const float* bch   = (const float*)d_in[9];
    const float* Wlz   = (const float*)d_in[10];
    const float* blz   = (const float*)d_in[11];
    // d_in[12], d_in[13] = Wlr, blr -- dead
    const float* Wlh   = (const float*)d_in[14];
    const float* blh   = (const float*)d_in[15];
    const float* Wout  = (const float*)d_in[16];
    const float* bout  = (const float*)d_in[17];
    float* out = (float*)d_out;

    const int N = in_sizes[0] / FEAT;
    const int E = in_sizes[2];
    const int* src = ei;
    const int* dst = ei + E;

    const int total4 = N * (FEAT / 4);
    const int NB7 = (N + 127) >> 7;      // bins at BB=7
    const int NB8 = (N + 255) >> 8;      // bins at BB=8

    // workspace layout
    char* base = (char*)d_ws;
    size_t o = 0;
    int*   cnt    = (int*)  (base + o); o += al256((size_t)N * 4);
    float* dinv   = (float*)(base + o); o += al256((size_t)N * 4);
    float* M      = (float*)(base + o); o += al256(1280 * 4);
    int2*  bucket = (int2*) (base + o); o += al256((size_t)N * CAP * 8);
    uint2* Xh2    = (uint2*)(base + o); o += al256((size_t)N * FEAT * 2);
    int*   cursor = (int*)  (base + o); o += al256(512 * 4);
    int2*  binned = (int2*) (base + o);
    size_t need7 = o + al256((size_t)NB7 * 3968 * 8);
    size_t need8 = o + al256((size_t)NB8 * 7168 * 8);

    if (ws_size >= need7 && NB7 <= 512 && N < (1 << 20)) {
        // BB=7: 391 bins; weights folded into pass1 block 0; cursor via memset
        hipMemsetAsync(cursor, 0, 512 * 4, stream);
        k_pass1<7, 3968><<<(E + EPB - 1) / EPB, 256, 0, stream>>>(src, dst, attr, cursor, binned, E,
                                                                  Wcz, bcz, Wch, bch, Wlz, blz, Wlh, blh, att, M);
        k_pass2x<7, 3968><<<NB7, 256, 0, stream>>>(cursor, binned, (const float4*)X, bucket, cnt, dinv, Xh2, N);
    } else if (ws_size >= need8 && NB8 <= 256 && N < (1 << 20)) {
        hipMemsetAsync(cursor, 0, 512 * 4, stream);
        k_pass1<8, 7168><<<(E + EPB - 1) / EPB, 256, 0, stream>>>(src, dst, attr, cursor, binned, E,
                                                                  Wcz, bcz, Wch, bch, Wlz, blz, Wlh, blh, att, M);
        k_pass2x<8, 7168><<<NB8, 256, 0, stream>>>(cursor, binned, (const float4*)X, bucket, cnt, dinv, Xh2, N);
    } else {
        k_weights<<<1, 256, 0, stream>>>(Wcz, bcz, Wch, bch, Wlz, blz, Wlh, blh, att, M);
        k_zero<<<(N + 255) / 256, 256, 0, stream>>>(cnt, N);
        k_bucket<<<(E + 255) / 256, 256, 0, stream>>>(src, dst, attr, cnt, bucket, E);
        k_dinv<<<((N * 64) + 255) / 256, 256, 0, stream>>>(cnt, bucket, dinv, N);
        k_xhalf<<<(total4 + 255) / 256, 256, 0, stream>>>((const float4*)X, dinv, Xh2, total4);
    }

    int blocks = (N + NB - 1) / NB;
    k_fused<<<blocks, 256, 0, stream>>>(cnt, bucket, dinv, Xh2, M, Wout, bout, out, N);
}